// Round 1
// baseline (114.728 us; speedup 1.0000x reference)
//
#include <hip/hip_runtime.h>
#include <math.h>

#define NB 8
#define NH 192
#define NW 192
#define NPTS 1000

#define TW 32   // tile width  (cells)
#define TH 12   // tile height (cells)
#define RPL 6   // rows per lane (64 lanes: 2 half-waves x 32 cols, 6 rows each)

constexpr float KDOWN = 8.0f;

// Workspace accumulators (zeroed every launch by init_acc; harness poisons ws).
struct Accum {
  double sums[NB][4];        // sp, spp, spt, stt
  unsigned int maxb[NB][2];  // max(pred), max(target) as order-preserving uint
};

__device__ __forceinline__ unsigned f2ord(float f) {
  unsigned u = __float_as_uint(f);
  return (u & 0x80000000u) ? ~u : (u | 0x80000000u);
}
__device__ __forceinline__ float ord2f(unsigned u) {
  unsigned b = (u & 0x80000000u) ? (u ^ 0x80000000u) : ~u;
  return __uint_as_float(b);
}

__global__ void init_acc(Accum* acc) {
  unsigned* p = reinterpret_cast<unsigned*>(acc);
  const int n = (int)(sizeof(Accum) / 4);  // 80 words
  int i = threadIdx.x;
  if (i < n) p[i] = 0u;  // 0 is below f2ord(x) for all x >= 0
}

__global__ __launch_bounds__(64) void heavy(const float* __restrict__ dens,
                                            const float* __restrict__ points,
                                            Accum* __restrict__ acc) {
  __shared__ float4 spts[NPTS];  // (px~, py~, q~, pad) relative to block center
  const int b = blockIdx.z;
  const int col0 = blockIdx.x * TW;
  const int row0 = blockIdx.y * TH;
  // block-center origin: keeps q-form cancellation error tiny for near points
  const float cx = (float)col0 * KDOWN + 128.0f;  // center of 32-cell span
  const float cy = (float)row0 * KDOWN + 48.0f;   // center of 12-cell span
  const int lane = threadIdx.x;

  const float2* __restrict__ pb =
      reinterpret_cast<const float2*>(points) + (size_t)b * NPTS;
  for (int j = lane; j < NPTS; j += 64) {
    float2 P = pb[j];
    float px = P.x - cx, py = P.y - cy;
    spts[j] = make_float4(px, py, __builtin_fmaf(px, px, py * py), 0.0f);
  }
  __syncthreads();

  const int c = lane & 31;
  const int rb = (lane >> 5) * RPL;
  const float xt = (float)(col0 + c) * KDOWN + 4.0f - cx;
  const float mx = -2.0f * xt;
  float yt[RPL], my[RPL], d2[RPL], p[RPL];
#pragma unroll
  for (int k = 0; k < RPL; ++k) {
    int row = row0 + rb + k;
    yt[k] = (float)row * KDOWN + 4.0f - cy;
    my[k] = -2.0f * yt[k];
    d2[k] = 3.0e38f;
    p[k] = dens[((size_t)b * NH + row) * NW + (col0 + c)];
  }

  // main loop: per point = 1 broadcast ds_read_b128 + 6 x (fma, fma, min)
#pragma unroll 8
  for (int j = 0; j < NPTS; ++j) {
    float4 P = spts[j];
#pragma unroll
    for (int k = 0; k < RPL; ++k) {
      float t = __builtin_fmaf(my[k], P.y, P.z);
      t = __builtin_fmaf(mx, P.x, t);
      d2[k] = fminf(d2[k], t);
    }
  }

  float sp = 0.f, spp = 0.f, sptv = 0.f, stt = 0.f, mp = 0.f, mt = 0.f;
#pragma unroll
  for (int k = 0; k < RPL; ++k) {
    float dd = fmaxf(d2[k] + __builtin_fmaf(xt, xt, yt[k] * yt[k]), 0.0f);
    float md = sqrtf(dd);
    float x = (8.0f - md) * 0.25f;
    float tg = 1.0f / (1.0f + __expf(-x));  // sigmoid((R - md)/(R/2))
    sp += p[k];
    spp = __builtin_fmaf(p[k], p[k], spp);
    sptv = __builtin_fmaf(p[k], tg, sptv);
    stt = __builtin_fmaf(tg, tg, stt);
    mp = fmaxf(mp, p[k]);
    mt = fmaxf(mt, tg);
  }

  // full-wave butterfly-free shfl_down reduce (width 64)
#pragma unroll
  for (int off = 32; off > 0; off >>= 1) {
    sp += __shfl_down(sp, off);
    spp += __shfl_down(spp, off);
    sptv += __shfl_down(sptv, off);
    stt += __shfl_down(stt, off);
    mp = fmaxf(mp, __shfl_down(mp, off));
    mt = fmaxf(mt, __shfl_down(mt, off));
  }
  if (lane == 0) {
    atomicAdd(&acc->sums[b][0], (double)sp);
    atomicAdd(&acc->sums[b][1], (double)spp);
    atomicAdd(&acc->sums[b][2], (double)sptv);
    atomicAdd(&acc->sums[b][3], (double)stt);
    atomicMax(&acc->maxb[b][0], f2ord(mp));
    atomicMax(&acc->maxb[b][1], f2ord(mt));
  }
}

__global__ void finalize(const Accum* __restrict__ acc, float* __restrict__ out) {
  if (threadIdx.x == 0 && blockIdx.x == 0) {
    double cls = 0.0, sls = 0.0, sps = 0.0;
    for (int b = 0; b < NB; ++b) {
      double sp = acc->sums[b][0];
      double pred_count = sp / 64.0;  // cell_area = 8*8
      double cl = fabs(pred_count - 1000.0);
      cls += cl;
      sls += cl / 1000.0;
      float pm = ord2f(acc->maxb[b][0]);
      float tm = ord2f(acc->maxb[b][1]);
      double pmc = fmax((double)pm, 1e-8);
      double tmc = fmax((double)tm, 1e-8);
      double spp = acc->sums[b][1];
      double sptv = acc->sums[b][2];
      double stt = acc->sums[b][3];
      // mean((p/pm - t/tm)^2) = (Spp/pm^2 - 2*Spt/(pm*tm) + Stt/tm^2) / (H*W)
      double mse = (spp / (pmc * pmc) - 2.0 * sptv / (pmc * tmc) +
                    stt / (tmc * tmc)) /
                   (double)(NH * NW);
      if (pm > 1e-8f && tm > 1e-8f) sps += mse;
    }
    out[0] = (float)(2.0 * (cls / NB) + 0.5 * (sls / NB) + 0.1 * (sps / NB));
  }
}

extern "C" void kernel_launch(void* const* d_in, const int* in_sizes, int n_in,
                              void* d_out, int out_size, void* d_ws,
                              size_t ws_size, hipStream_t stream) {
  const float* dens = (const float*)d_in[0];    // (B,1,H,W) f32
  const float* points = (const float*)d_in[1];  // (B,N,2)  f32
  Accum* acc = (Accum*)d_ws;
  float* out = (float*)d_out;

  hipLaunchKernelGGL(init_acc, dim3(1), dim3(128), 0, stream, acc);
  dim3 grid(NW / TW, NH / TH, NB);  // 6 x 16 x 8 = 768 one-wave blocks
  hipLaunchKernelGGL(heavy, grid, dim3(64), 0, stream, dens, points, acc);
  hipLaunchKernelGGL(finalize, dim3(1), dim3(64), 0, stream, acc, out);
}

// Round 2
// 64.911 us; speedup vs baseline: 1.7675x; 1.7675x over previous
//
#include <hip/hip_runtime.h>
#include <math.h>

#define NB 8
#define NH 192
#define NW 192
#define NPTS 1000
#define TW 32
#define TH 12
#define NPIX (TW * TH)  // 384

constexpr float KDOWN = 8.0f;

// ws layout: float parts[768][8] = {sp, spp, spt, stt, mp, mt, pad, pad}
// written unconditionally by every block -> no init kernel needed.

__global__ __launch_bounds__(256) void heavy(const float* __restrict__ dens,
                                             const float* __restrict__ points,
                                             float* __restrict__ parts) {
  __shared__ float4 kept[NPTS];       // 16000 B
  __shared__ float d2all[4][NPIX];    // 6144 B
  __shared__ float wmin[4];
  __shared__ float sred[4][6];
  __shared__ int scnt;

  const int b = blockIdx.z;
  const int col0 = blockIdx.x * TW;
  const int row0 = blockIdx.y * TH;
  const float cx = (float)col0 * KDOWN + 128.0f;  // tile-center origin (as r1)
  const float cy = (float)row0 * KDOWN + 48.0f;
  const int tid = threadIdx.x;
  const int lane = tid & 63;
  const int w = tid >> 6;

  // --- prefetch dens for epilogue early (hide HBM latency under everything) ---
  const int prow = tid >> 5;  // 0..7
  const int pcol = tid & 31;
  float pred0 = dens[((size_t)b * NH + row0 + prow) * NW + col0 + pcol];
  float pred1 = 0.0f;
  if (tid < 128)
    pred1 = dens[((size_t)b * NH + row0 + 8 + prow) * NW + col0 + pcol];

  if (tid == 0) scnt = 0;

  const float2* __restrict__ pb =
      reinterpret_cast<const float2*>(points) + (size_t)b * NPTS;

  // --- phase 0: min squared center-distance over all 1000 points ---
  float2 P0[4];
#pragma unroll
  for (int r = 0; r < 4; ++r) {
    int j = r * 256 + tid;
    P0[r] = (j < NPTS) ? pb[j] : make_float2(1.0e19f, 1.0e19f);
  }
  float qmin = 3.0e38f;
#pragma unroll
  for (int r = 0; r < 4; ++r) {
    int j = r * 256 + tid;
    if (j < NPTS) {
      float px = P0[r].x - cx, py = P0[r].y - cy;
      qmin = fminf(qmin, __builtin_fmaf(px, px, py * py));
    }
  }
#pragma unroll
  for (int off = 32; off > 0; off >>= 1)
    qmin = fminf(qmin, __shfl_down(qmin, off));
  if (lane == 0) wmin[w] = qmin;
  __syncthreads();

  const float M2 = fminf(fminf(wmin[0], wmin[1]), fminf(wmin[2], wmin[3]));
  // keep j iff dist(center,j) <= min_dist + 2*halfdiag (+1 rounding pad).
  // halfdiag over PIXEL CENTERS = sqrt(124^2 + 44^2) = 131.576
  const float thr = sqrtf(M2) + 2.0f * 131.58f + 1.0f;
  const float T = thr * thr;

  // --- phase 1: ballot-compact qualifying points into LDS (exact pruning) ---
#pragma unroll
  for (int r = 0; r < 4; ++r) {
    int j = r * 256 + tid;
    bool keep = false;
    float px = 0.f, py = 0.f, q = 0.f;
    if (j < NPTS) {
      px = P0[r].x - cx;
      py = P0[r].y - cy;
      q = __builtin_fmaf(px, px, py * py);
      keep = (q <= T);
    }
    unsigned long long mask = __ballot(keep);
    int base = 0;
    if (lane == 0) base = atomicAdd(&scnt, __popcll(mask));
    base = __shfl(base, 0);
    if (keep) {
      int pos = base + __popcll(mask & ((1ull << lane) - 1ull));
      kept[pos] = make_float4(px, py, q, 0.0f);
    }
  }
  __syncthreads();
  const int cnt = scnt;  // >= 1 always (the argmin point survives)

  // --- phase 2: per-wave min over its strided quarter of kept[] ---
  const int c = lane & 31;
  const int half = lane >> 5;
  const float xt = (float)(col0 + c) * KDOWN + 4.0f - cx;
  const float mx = -2.0f * xt;
  float my[6], xy2[6], d2[6];
#pragma unroll
  for (int k = 0; k < 6; ++k) {
    float ytk = (float)(row0 + half * 6 + k) * KDOWN + 4.0f - cy;
    my[k] = -2.0f * ytk;
    xy2[k] = __builtin_fmaf(xt, xt, ytk * ytk);
    d2[k] = 3.0e38f;
  }

  if (cnt > w) {
    const int M = (cnt - w + 3) >> 2;  // points for this wave, 4-batched
    auto IDX = [&](int m) { m = (m < M) ? m : (M - 1); return w + 4 * m; };
    // register double-buffer, 4 points deep: hides ds_read broadcast latency
    float4 A0 = kept[IDX(0)], A1 = kept[IDX(1)], A2 = kept[IDX(2)],
           A3 = kept[IDX(3)];
    for (int i0 = 0; i0 < M; i0 += 4) {
      float4 B0 = kept[IDX(i0 + 4)], B1 = kept[IDX(i0 + 5)],
             B2 = kept[IDX(i0 + 6)], B3 = kept[IDX(i0 + 7)];
#pragma unroll
      for (int k = 0; k < 6; ++k) {
        float t0 = __builtin_fmaf(my[k], A0.y, A0.z);
        t0 = __builtin_fmaf(mx, A0.x, t0);
        float t1 = __builtin_fmaf(my[k], A1.y, A1.z);
        t1 = __builtin_fmaf(mx, A1.x, t1);
        float t2 = __builtin_fmaf(my[k], A2.y, A2.z);
        t2 = __builtin_fmaf(mx, A2.x, t2);
        float t3 = __builtin_fmaf(my[k], A3.y, A3.z);
        t3 = __builtin_fmaf(mx, A3.x, t3);
        d2[k] = fminf(d2[k], fminf(fminf(t0, t1), fminf(t2, t3)));
      }
      A0 = B0; A1 = B1; A2 = B2; A3 = B3;
    }
  }

  // absolute d2 (monotone shift commutes with min -> bit-identical to r1)
#pragma unroll
  for (int k = 0; k < 6; ++k)
    d2all[w][(half * 6 + k) * TW + c] = d2[k] + xy2[k];
  __syncthreads();

  // --- phase 3: epilogue, 1-2 pixels/thread ---
  float sp = 0.f, spp = 0.f, spt = 0.f, stt = 0.f, mp = 0.f, mt = 0.f;
  {
    int p = tid;
    float m4 = fminf(fminf(d2all[0][p], d2all[1][p]),
                     fminf(d2all[2][p], d2all[3][p]));
    float dd = fmaxf(m4, 0.0f);
    float md = sqrtf(dd);
    float x = (8.0f - md) * 0.25f;
    float tg = 1.0f / (1.0f + __expf(-x));
    sp += pred0;
    spp = __builtin_fmaf(pred0, pred0, spp);
    spt = __builtin_fmaf(pred0, tg, spt);
    stt = __builtin_fmaf(tg, tg, stt);
    mp = fmaxf(mp, pred0);
    mt = fmaxf(mt, tg);
  }
  if (tid < 128) {
    int p = tid + 256;
    float m4 = fminf(fminf(d2all[0][p], d2all[1][p]),
                     fminf(d2all[2][p], d2all[3][p]));
    float dd = fmaxf(m4, 0.0f);
    float md = sqrtf(dd);
    float x = (8.0f - md) * 0.25f;
    float tg = 1.0f / (1.0f + __expf(-x));
    sp += pred1;
    spp = __builtin_fmaf(pred1, pred1, spp);
    spt = __builtin_fmaf(pred1, tg, spt);
    stt = __builtin_fmaf(tg, tg, stt);
    mp = fmaxf(mp, pred1);
    mt = fmaxf(mt, tg);
  }

#pragma unroll
  for (int off = 32; off > 0; off >>= 1) {
    sp += __shfl_down(sp, off);
    spp += __shfl_down(spp, off);
    spt += __shfl_down(spt, off);
    stt += __shfl_down(stt, off);
    mp = fmaxf(mp, __shfl_down(mp, off));
    mt = fmaxf(mt, __shfl_down(mt, off));
  }
  if (lane == 0) {
    sred[w][0] = sp; sred[w][1] = spp; sred[w][2] = spt;
    sred[w][3] = stt; sred[w][4] = mp; sred[w][5] = mt;
  }
  __syncthreads();
  if (tid == 0) {
    const int bid =
        blockIdx.x + gridDim.x * (blockIdx.y + gridDim.y * blockIdx.z);
    float o[6];
#pragma unroll
    for (int i = 0; i < 4; ++i)
      o[i] = (sred[0][i] + sred[1][i]) + (sred[2][i] + sred[3][i]);
    o[4] = fmaxf(fmaxf(sred[0][4], sred[1][4]), fmaxf(sred[2][4], sred[3][4]));
    o[5] = fmaxf(fmaxf(sred[0][5], sred[1][5]), fmaxf(sred[2][5], sred[3][5]));
    float* dst = parts + (size_t)bid * 8;
#pragma unroll
    for (int i = 0; i < 6; ++i) dst[i] = o[i];
  }
}

__global__ __launch_bounds__(512) void finalize(const float* __restrict__ parts,
                                                float* __restrict__ out) {
  __shared__ double dres[8][3];
  const int tid = threadIdx.x;
  const int w = tid >> 6;   // = batch
  const int lane = tid & 63;

  double sp = 0, spp = 0, spt = 0, stt = 0;
  float mp = 0.f, mt = 0.f;
  for (int e = lane; e < 96; e += 64) {
    const float* src = parts + (size_t)(w * 96 + e) * 8;
    sp += (double)src[0];
    spp += (double)src[1];
    spt += (double)src[2];
    stt += (double)src[3];
    mp = fmaxf(mp, src[4]);
    mt = fmaxf(mt, src[5]);
  }
#pragma unroll
  for (int off = 32; off > 0; off >>= 1) {
    sp += __shfl_down(sp, off);
    spp += __shfl_down(spp, off);
    spt += __shfl_down(spt, off);
    stt += __shfl_down(stt, off);
    mp = fmaxf(mp, __shfl_down(mp, off));
    mt = fmaxf(mt, __shfl_down(mt, off));
  }
  if (lane == 0) {
    double cl = fabs(sp / 64.0 - 1000.0);  // cell_area = 64, gt = 1000
    double pm = fmax((double)mp, 1e-8);
    double tm = fmax((double)mt, 1e-8);
    double mse =
        (spp / (pm * pm) - 2.0 * spt / (pm * tm) + stt / (tm * tm)) / 36864.0;
    double sps = (mp > 1e-8f && mt > 1e-8f) ? mse : 0.0;
    dres[w][0] = cl;
    dres[w][1] = cl / 1000.0;
    dres[w][2] = sps;
  }
  __syncthreads();
  if (tid == 0) {
    double cls = 0, sls = 0, sps = 0;
    for (int bb = 0; bb < 8; ++bb) {
      cls += dres[bb][0];
      sls += dres[bb][1];
      sps += dres[bb][2];
    }
    out[0] = (float)(2.0 * (cls / 8.0) + 0.5 * (sls / 8.0) + 0.1 * (sps / 8.0));
  }
}

extern "C" void kernel_launch(void* const* d_in, const int* in_sizes, int n_in,
                              void* d_out, int out_size, void* d_ws,
                              size_t ws_size, hipStream_t stream) {
  const float* dens = (const float*)d_in[0];    // (B,1,H,W) f32
  const float* points = (const float*)d_in[1];  // (B,N,2)  f32
  float* parts = (float*)d_ws;                  // 768*8 floats = 24.6 KB
  float* out = (float*)d_out;

  dim3 grid(NW / TW, NH / TH, NB);  // (6,16,8) = 768 blocks, 4 waves each
  hipLaunchKernelGGL(heavy, grid, dim3(256), 0, stream, dens, points, parts);
  hipLaunchKernelGGL(finalize, dim3(1), dim3(512), 0, stream, parts, out);
}

// Round 3
// 64.041 us; speedup vs baseline: 1.7915x; 1.0136x over previous
//
#include <hip/hip_runtime.h>
#include <math.h>

#define NB 8
#define NH 192
#define NW 192
#define NPTS 1000
#define TW 32
#define TH 12
#define NPIX (TW * TH)  // 384

constexpr float KDOWN = 8.0f;

// ws layout: float parts[768][8] = {sp, spp, spt, stt, mp, mt, pad, pad},
// batch-major (bid = b*96 + tile). Written unconditionally by every block.

__global__ __launch_bounds__(512) void heavy(const float* __restrict__ dens,
                                             const float* __restrict__ points,
                                             float* __restrict__ parts) {
  __shared__ float4 kept[8][128];   // per-wave private compacted points, 16 KB
  __shared__ float d2all[8][NPIX];  // per-wave pixel min, 12 KB
  __shared__ float wmin[8];
  __shared__ float sred[6][6];      // waves 0..5 carry epilogue stats

  const int b = blockIdx.z;
  const int col0 = blockIdx.x * TW;
  const int row0 = blockIdx.y * TH;
  const float cx = (float)col0 * KDOWN + 128.0f;  // tile-center origin
  const float cy = (float)row0 * KDOWN + 48.0f;
  const int tid = threadIdx.x;
  const int lane = tid & 63;
  const int w = tid >> 6;  // wave 0..7

  // --- prefetch dens early (1 px/thread for tid<384) ---
  float pred0 = 0.0f;
  if (tid < NPIX)
    pred0 = dens[((size_t)b * NH + row0 + (tid >> 5)) * NW + col0 + (tid & 31)];

  // --- phase 0: each wave loads its 1/8 of points (2 candidates/lane) ---
  const float2* __restrict__ pb =
      reinterpret_cast<const float2*>(points) + (size_t)b * NPTS;
  const int j0 = w * 64 + lane;        // always < 512 < NPTS
  const int j1 = 512 + j0;             // valid iff < NPTS
  const bool v1 = (j1 < NPTS);
  float2 P0 = pb[j0];
  float2 P1 = v1 ? pb[j1] : make_float2(1.0e19f, 1.0e19f);
  const float p0x = P0.x - cx, p0y = P0.y - cy;
  const float p1x = P1.x - cx, p1y = P1.y - cy;
  const float q0 = __builtin_fmaf(p0x, p0x, p0y * p0y);
  const float q1 = __builtin_fmaf(p1x, p1x, p1y * p1y);

  float qmin = fminf(q0, v1 ? q1 : 3.0e38f);
#pragma unroll
  for (int off = 32; off > 0; off >>= 1)
    qmin = fminf(qmin, __shfl_down(qmin, off));
  if (lane == 0) wmin[w] = qmin;
  __syncthreads();  // barrier 1

  float M2 = wmin[0];
#pragma unroll
  for (int i = 1; i < 8; ++i) M2 = fminf(M2, wmin[i]);
  // exact prune: keep j iff dist(c,j) <= min_k dist(c,k) + 2*halfdiag (+1 pad)
  // halfdiag over pixel centers = sqrt(124^2+44^2) = 131.576
  const float thr = sqrtf(M2) + 2.0f * 131.58f + 1.0f;
  const float T = thr * thr;

  // --- phase 1: per-wave ballot compaction into private LDS segment ---
  const bool k0 = (q0 <= T);
  const bool k1 = v1 && (q1 <= T);
  const unsigned long long m0 = __ballot(k0);
  const unsigned long long m1 = __ballot(k1);
  const unsigned long long below = (lane == 63) ? ~0ull : ((1ull << (lane + 1)) - 1ull) >> 1;
  if (k0) kept[w][__popcll(m0 & below)] = make_float4(p0x, p0y, q0, 0.0f);
  if (k1) kept[w][__popcll(m0) + __popcll(m1 & below)] =
      make_float4(p1x, p1y, q1, 0.0f);
  const int M = __popcll(m0) + __popcll(m1);  // this wave's kept count (wave-uniform)

  // --- phase 2: this wave scans its own list over all 384 pixels ---
  const int c = lane & 31;
  const int half = lane >> 5;
  const float xt = (float)(col0 + c) * KDOWN + 4.0f - cx;
  const float mx = -2.0f * xt;
  float my[6], xy2[6], d2[6];
#pragma unroll
  for (int k = 0; k < 6; ++k) {
    float ytk = (float)(row0 + half * 6 + k) * KDOWN + 4.0f - cy;
    my[k] = -2.0f * ytk;
    xy2[k] = __builtin_fmaf(xt, xt, ytk * ytk);
    d2[k] = 3.0e38f;
  }
  // no cross-wave sync needed: each wave reads only its own segment,
  // written by itself (wave-coherent LDS), but the compiler needs the
  // ds_writes ordered before ds_reads within the wave -- it is (same lane
  // ordering not required: reads are broadcast of other lanes' writes).
  __builtin_amdgcn_wave_barrier();
  asm volatile("s_waitcnt lgkmcnt(0)" ::: "memory");

  const int Mc = (M > 0) ? M : 1;  // segment has >=1 valid iff M>0
  if (M > 0) {
    for (int i0 = 0; i0 < Mc; i0 += 4) {
      int i1 = (i0 + 1 < Mc) ? i0 + 1 : Mc - 1;
      int i2 = (i0 + 2 < Mc) ? i0 + 2 : Mc - 1;
      int i3 = (i0 + 3 < Mc) ? i0 + 3 : Mc - 1;
      float4 A0 = kept[w][i0], A1 = kept[w][i1], A2 = kept[w][i2],
             A3 = kept[w][i3];
#pragma unroll
      for (int k = 0; k < 6; ++k) {
        float t0 = __builtin_fmaf(mx, A0.x, __builtin_fmaf(my[k], A0.y, A0.z));
        float t1 = __builtin_fmaf(mx, A1.x, __builtin_fmaf(my[k], A1.y, A1.z));
        float t2 = __builtin_fmaf(mx, A2.x, __builtin_fmaf(my[k], A2.y, A2.z));
        float t3 = __builtin_fmaf(mx, A3.x, __builtin_fmaf(my[k], A3.y, A3.z));
        d2[k] = fminf(d2[k], fminf(fminf(t0, t1), fminf(t2, t3)));
      }
    }
  }
#pragma unroll
  for (int k = 0; k < 6; ++k)
    d2all[w][(half * 6 + k) * TW + c] = d2[k] + xy2[k];
  __syncthreads();  // barrier 2

  // --- phase 3: epilogue, 1 px/thread for tid<384, 8-way min across waves ---
  float sp = 0.f, spp = 0.f, spt = 0.f, stt = 0.f, mp = 0.f, mt = 0.f;
  if (tid < NPIX) {
    float m8 = d2all[0][tid];
#pragma unroll
    for (int i = 1; i < 8; ++i) m8 = fminf(m8, d2all[i][tid]);
    float md = sqrtf(fmaxf(m8, 0.0f));
    float x = (8.0f - md) * 0.25f;
    float tg = 1.0f / (1.0f + __expf(-x));  // sigmoid((R-md)/(R/2))
    sp = pred0;
    spp = pred0 * pred0;
    spt = pred0 * tg;
    stt = tg * tg;
    mp = pred0;
    mt = tg;
  }
#pragma unroll
  for (int off = 32; off > 0; off >>= 1) {
    sp += __shfl_down(sp, off);
    spp += __shfl_down(spp, off);
    spt += __shfl_down(spt, off);
    stt += __shfl_down(stt, off);
    mp = fmaxf(mp, __shfl_down(mp, off));
    mt = fmaxf(mt, __shfl_down(mt, off));
  }
  if (lane == 0 && w < 6) {
    sred[w][0] = sp; sred[w][1] = spp; sred[w][2] = spt;
    sred[w][3] = stt; sred[w][4] = mp; sred[w][5] = mt;
  }
  __syncthreads();  // barrier 3
  if (tid == 0) {
    float o[6];
#pragma unroll
    for (int i = 0; i < 4; ++i)
      o[i] = ((sred[0][i] + sred[1][i]) + (sred[2][i] + sred[3][i])) +
             (sred[4][i] + sred[5][i]);
    o[4] = fmaxf(fmaxf(fmaxf(sred[0][4], sred[1][4]),
                       fmaxf(sred[2][4], sred[3][4])),
                 fmaxf(sred[4][4], sred[5][4]));
    o[5] = fmaxf(fmaxf(fmaxf(sred[0][5], sred[1][5]),
                       fmaxf(sred[2][5], sred[3][5])),
                 fmaxf(sred[4][5], sred[5][5]));
    const int bid = b * 96 + blockIdx.y * gridDim.x + blockIdx.x;
    float* dst = parts + (size_t)bid * 8;
#pragma unroll
    for (int i = 0; i < 6; ++i) dst[i] = o[i];
  }
}

__global__ __launch_bounds__(512) void finalize(const float* __restrict__ parts,
                                                float* __restrict__ out) {
  __shared__ double dres[8][3];
  const int tid = threadIdx.x;
  const int w = tid >> 6;  // = batch
  const int lane = tid & 63;

  double sp = 0, spp = 0, spt = 0, stt = 0;
  float mp = 0.f, mt = 0.f;
  for (int e = lane; e < 96; e += 64) {
    const float* src = parts + (size_t)(w * 96 + e) * 8;
    sp += (double)src[0];
    spp += (double)src[1];
    spt += (double)src[2];
    stt += (double)src[3];
    mp = fmaxf(mp, src[4]);
    mt = fmaxf(mt, src[5]);
  }
#pragma unroll
  for (int off = 32; off > 0; off >>= 1) {
    sp += __shfl_down(sp, off);
    spp += __shfl_down(spp, off);
    spt += __shfl_down(spt, off);
    stt += __shfl_down(stt, off);
    mp = fmaxf(mp, __shfl_down(mp, off));
    mt = fmaxf(mt, __shfl_down(mt, off));
  }
  if (lane == 0) {
    double cl = fabs(sp / 64.0 - 1000.0);  // cell_area = 64, gt = 1000
    double pm = fmax((double)mp, 1e-8);
    double tm = fmax((double)mt, 1e-8);
    double mse =
        (spp / (pm * pm) - 2.0 * spt / (pm * tm) + stt / (tm * tm)) / 36864.0;
    double sps = (mp > 1e-8f && mt > 1e-8f) ? mse : 0.0;
    dres[w][0] = cl;
    dres[w][1] = cl / 1000.0;
    dres[w][2] = sps;
  }
  __syncthreads();
  if (tid == 0) {
    double cls = 0, sls = 0, sps = 0;
    for (int bb = 0; bb < 8; ++bb) {
      cls += dres[bb][0];
      sls += dres[bb][1];
      sps += dres[bb][2];
    }
    out[0] = (float)(2.0 * (cls / 8.0) + 0.5 * (sls / 8.0) + 0.1 * (sps / 8.0));
  }
}

extern "C" void kernel_launch(void* const* d_in, const int* in_sizes, int n_in,
                              void* d_out, int out_size, void* d_ws,
                              size_t ws_size, hipStream_t stream) {
  const float* dens = (const float*)d_in[0];    // (B,1,H,W) f32
  const float* points = (const float*)d_in[1];  // (B,N,2)  f32
  float* parts = (float*)d_ws;                  // 768*8 floats = 24.6 KB
  float* out = (float*)d_out;

  dim3 grid(NW / TW, NH / TH, NB);  // (6,16,8) = 768 blocks, 8 waves each
  hipLaunchKernelGGL(heavy, grid, dim3(512), 0, stream, dens, points, parts);
  hipLaunchKernelGGL(finalize, dim3(1), dim3(512), 0, stream, parts, out);
}